// Round 7
// baseline (156.761 us; speedup 1.0000x reference)
//
#include <hip/hip_runtime.h>
#include <hip/hip_bf16.h>

#define GRID_RES 32
#define GRID_DIM 8
#define N_CELLS  256
#define EMB_VOL  512
#define TAB_N    (GRID_RES * GRID_RES * GRID_RES)   // 32768
#define NPT      4
#define BLOCK    512

__device__ __forceinline__ unsigned bf16rne(float f) {
    unsigned u = __float_as_uint(f);
    return (u + 0x7fffu + ((u >> 16) & 1u)) >> 16;
}
__device__ __forceinline__ float bf16lo(unsigned u) { return __uint_as_float(u << 16); }
__device__ __forceinline__ float bf16hi(unsigned u) { return __uint_as_float(u & 0xffff0000u); }

// ---------------- pre-pass: per-cell 2x2x2 corner cube, bf16 x8 = 16B ----------------
// cube[b*512 + (lx*8+ly)*8 + lz] = uint4{ c000|c001<<16, c010|c011<<16,
//                                         c100|c101<<16, c110|c111<<16 }
// where c_{dx,dy,dz} = value at cell (8*B + (lx,ly,lz) + (dx,dy,dz)), 0 if that
// corner's block is unallocated. One thread per (table entry, lx, ly) row.
__global__ __launch_bounds__(256) void build_cubes(
    const float* __restrict__ emb, const int* __restrict__ table,
    uint4* __restrict__ cube)
{
    int tid = blockIdx.x * 256 + threadIdx.x;
    int entry = tid >> 6;
    if (entry >= TAB_N) return;
    int b = table[entry];
    if (b < 0) return;
    int r  = tid & 63;
    int lx = r >> 3, ly = r & 7;
    int BX = entry >> 10, BY = (entry >> 5) & 31, BZ = entry & 31;

    float v[4][9];
#pragma unroll
    for (int i = 0; i < 4; ++i) {
        int ax = lx + (i >> 1), ay = ly + (i & 1);
        int sx = ax >> 3, sy = ay >> 3;
        bool ok = (BX + sx < GRID_RES) && (BY + sy < GRID_RES);
        int ex = entry + sx * 1024 + sy * 32;
        int rb = ok ? table[ex] : -1;
        int lxl = ax & 7, lyl = ay & 7;
        if (rb >= 0) {
            const float* src = emb + (size_t)rb * EMB_VOL + (lxl * 8 + lyl) * 8;
            float4 a0 = *reinterpret_cast<const float4*>(src);
            float4 a1 = *reinterpret_cast<const float4*>(src + 4);
            v[i][0]=a0.x; v[i][1]=a0.y; v[i][2]=a0.z; v[i][3]=a0.w;
            v[i][4]=a1.x; v[i][5]=a1.y; v[i][6]=a1.z; v[i][7]=a1.w;
        } else {
#pragma unroll
            for (int z = 0; z < 8; ++z) v[i][z] = 0.0f;
        }
        int zb = (ok && (BZ + 1 < GRID_RES)) ? table[ex + 1] : -1;
        v[i][8] = (zb >= 0) ? emb[(size_t)zb * EMB_VOL + (lxl * 8 + lyl) * 8] : 0.0f;
    }

    uint4* dst = cube + ((size_t)b * EMB_VOL + (lx * 8 + ly) * 8);
#pragma unroll
    for (int lz = 0; lz < 8; ++lz) {
        unsigned u0 = bf16rne(v[0][lz]) | (bf16rne(v[0][lz + 1]) << 16);
        unsigned u1 = bf16rne(v[1][lz]) | (bf16rne(v[1][lz + 1]) << 16);
        unsigned u2 = bf16rne(v[2][lz]) | (bf16rne(v[2][lz + 1]) << 16);
        unsigned u3 = bf16rne(v[3][lz]) | (bf16rne(v[3][lz + 1]) << 16);
        dst[lz] = make_uint4(u0, u1, u2, u3);
    }
}

// ---------------- main: LDS table, ONE 16B gather per point ----------------
__global__ __launch_bounds__(BLOCK) void interp_cubes(
    const float* __restrict__ positions,
    const float* __restrict__ emb,         // fp32 originals (rare fallback)
    const int*   __restrict__ table,
    const uint4* __restrict__ cube,
    float* __restrict__ out, int n)
{
    __shared__ short stab[TAB_N];          // 64 KB
    {
        const int4* t4 = reinterpret_cast<const int4*>(table);
        for (int k = threadIdx.x; k < TAB_N / 4; k += BLOCK) {
            int4 v = t4[k];
            short4 s;
            s.x = (short)v.x; s.y = (short)v.y; s.z = (short)v.z; s.w = (short)v.w;
            *reinterpret_cast<short4*>(&stab[4 * k]) = s;
        }
    }
    __syncthreads();

    int nq = (n + NPT - 1) / NPT;
    int stride = gridDim.x * BLOCK;
    for (int q = blockIdx.x * BLOCK + threadIdx.x; q < nq; q += stride) {
        int i0 = q * NPT;
        bool full = (i0 + NPT <= n);

        float px[NPT], py[NPT], pz[NPT];
        if (full) {
            const float4* p4 = reinterpret_cast<const float4*>(positions + 3 * (size_t)i0);
            float4 A = p4[0], B = p4[1], C = p4[2];
            px[0]=A.x; py[0]=A.y; pz[0]=A.z;
            px[1]=A.w; py[1]=B.x; pz[1]=B.y;
            px[2]=B.z; py[2]=B.w; pz[2]=C.x;
            px[3]=C.y; py[3]=C.z; pz[3]=C.w;
        } else {
#pragma unroll
            for (int p = 0; p < NPT; ++p) {
                int ip = min(i0 + p, n - 1);
                px[p] = positions[3 * ip + 0];
                py[p] = positions[3 * ip + 1];
                pz[p] = positions[3 * ip + 2];
            }
        }

        float wA[NPT][3], wB[NPT][3];
        int bxv[NPT], byv[NPT], bzv[NPT];
        short tc[NPT][8];                 // corner-block table values
        uint4 cu[NPT];

#pragma unroll
        for (int p = 0; p < NPT; ++p) {
            float xc[3];
            xc[0] = (px[p] + 1.0f) * 0.5f * (float)(N_CELLS - 1);
            xc[1] = (py[p] + 1.0f) * 0.5f * (float)(N_CELLS - 1);
            xc[2] = (pz[p] + 1.0f) * 0.5f * (float)(N_CELLS - 1);
            int base[3];
#pragma unroll
            for (int a = 0; a < 3; ++a) {
                float bf = fminf(fmaxf(floorf(xc[a]), 0.0f), (float)(N_CELLS - 2));
                float fr = xc[a] - bf;
                wA[p][a] = 1.0f - fr;
                wB[p][a] = fr;
                base[a] = (int)bf;
            }
            int bx = base[0], by = base[1], bz = base[2];
            bxv[p] = bx; byv[p] = by; bzv[p] = bz;
            int eidx = ((bx >> 3) * GRID_RES + (by >> 3)) * GRID_RES + (bz >> 3);
            int ox = ((bx & 7) == 7) ? (GRID_RES * GRID_RES) : 0;
            int oy = ((by & 7) == 7) ? GRID_RES : 0;
            int oz = ((bz & 7) == 7) ? 1 : 0;
            tc[p][0] = stab[eidx];
            tc[p][1] = stab[eidx + oz];
            tc[p][2] = stab[eidx + oy];
            tc[p][3] = stab[eidx + oy + oz];
            tc[p][4] = stab[eidx + ox];
            tc[p][5] = stab[eidx + ox + oz];
            tc[p][6] = stab[eidx + ox + oy];
            tc[p][7] = stab[eidx + ox + oy + oz];
        }

        // one 16B gather per point
#pragma unroll
        for (int p = 0; p < NPT; ++p) {
            int b = tc[p][0] > 0 ? tc[p][0] : 0;
            int cell = ((bxv[p] & 7) * 8 + (byv[p] & 7)) * 8 + (bzv[p] & 7);
            cu[p] = cube[(size_t)b * EMB_VOL + cell];
        }

        const float scale = 0.5f * (float)(N_CELLS - 1);  // 127.5
        float acc[NPT], gxv[NPT], gyv[NPT], gzv[NPT], mk[NPT];

#pragma unroll
        for (int p = 0; p < NPT; ++p) {
            float e[4][2];
            e[0][0] = bf16lo(cu[p].x); e[0][1] = bf16hi(cu[p].x);
            e[1][0] = bf16lo(cu[p].y); e[1][1] = bf16hi(cu[p].y);
            e[2][0] = bf16lo(cu[p].z); e[2][1] = bf16hi(cu[p].z);
            e[3][0] = bf16lo(cu[p].w); e[3][1] = bf16hi(cu[p].w);

            if (tc[p][0] < 0) {
                // base block unallocated: cube read was garbage -> rebuild the
                // (rare) valid corners exactly from fp32 source.
#pragma unroll
                for (int i = 0; i < 4; ++i) { e[i][0] = 0.0f; e[i][1] = 0.0f; }
#pragma unroll
                for (int c = 0; c < 8; ++c) {
                    int dx = c >> 2, dy = (c >> 1) & 1, dz = c & 1;
                    short t = tc[p][c];
                    if (t >= 0) {
                        int cx = bxv[p] + dx, cy = byv[p] + dy, cz = bzv[p] + dz;
                        int li = ((cx & 7) * 8 + (cy & 7)) * 8 + (cz & 7);
                        e[dx * 2 + dy][dz] = emb[(size_t)t * EMB_VOL + li];
                    }
                }
            }

            int sgn = tc[p][0] & tc[p][1] & tc[p][2] & tc[p][3] &
                      tc[p][4] & tc[p][5] & tc[p][6] & tc[p][7];
            float wz0 = wA[p][2], wz1 = wB[p][2];
            float a = 0.0f, gx = 0.0f, gy = 0.0f, gz = 0.0f;
#pragma unroll
            for (int i = 0; i < 4; ++i) {
                int dx = i >> 1, dy = i & 1;
                float e0 = e[i][0], e1 = e[i][1];
                float s = wz0 * e0 + wz1 * e1;
                float wx = dx ? wB[p][0] : wA[p][0];
                float wy = dy ? wB[p][1] : wA[p][1];
                float wxy = wx * wy;
                a  += wxy * s;
                gx += dx ? wy * s : -wy * s;
                gy += dy ? wx * s : -wx * s;
                gz += wxy * (e1 - e0);
            }
            acc[p] = a;
            gxv[p] = scale * gx;
            gyv[p] = scale * gy;
            gzv[p] = scale * gz;
            mk[p]  = (sgn >= 0) ? 1.0f : 0.0f;
        }

        float* out_emb  = out;
        float* out_grad = out + (size_t)n;
        float* out_mask = out + 4 * (size_t)n;

        if (full) {
            *reinterpret_cast<float4*>(out_emb + i0) =
                make_float4(acc[0], acc[1], acc[2], acc[3]);
            float4* g4 = reinterpret_cast<float4*>(out_grad + 3 * (size_t)i0);
            g4[0] = make_float4(gxv[0], gyv[0], gzv[0], gxv[1]);
            g4[1] = make_float4(gyv[1], gzv[1], gxv[2], gyv[2]);
            g4[2] = make_float4(gzv[2], gxv[3], gyv[3], gzv[3]);
            *reinterpret_cast<float4*>(out_mask + i0) =
                make_float4(mk[0], mk[1], mk[2], mk[3]);
        } else {
#pragma unroll
            for (int p = 0; p < NPT; ++p) {
                int ip = i0 + p;
                if (ip < n) {
                    out_emb[ip]          = acc[p];
                    out_grad[3 * ip + 0] = gxv[p];
                    out_grad[3 * ip + 1] = gyv[p];
                    out_grad[3 * ip + 2] = gzv[p];
                    out_mask[ip]         = mk[p];
                }
            }
        }
    }
}

// ---------------- fallback (R5 kernel) if ws_size too small ----------------
__global__ __launch_bounds__(BLOCK) void neural_poisson_interp(
    const float* __restrict__ positions,
    const float* __restrict__ embeddings,
    const int*   __restrict__ block_table,
    float* __restrict__ out, int n)
{
    __shared__ short stab[TAB_N];
    {
        const int4* t4 = reinterpret_cast<const int4*>(block_table);
        for (int k = threadIdx.x; k < TAB_N / 4; k += BLOCK) {
            int4 v = t4[k];
            short4 s;
            s.x = (short)v.x; s.y = (short)v.y; s.z = (short)v.z; s.w = (short)v.w;
            *reinterpret_cast<short4*>(&stab[4 * k]) = s;
        }
    }
    __syncthreads();

    int t = blockIdx.x * blockDim.x + threadIdx.x;
    int i0 = t * NPT;
    if (i0 >= n) return;
    bool full = (i0 + NPT <= n);

    float px[NPT], py[NPT], pz[NPT];
    if (full) {
        const float4* p4 = reinterpret_cast<const float4*>(positions + 3 * (size_t)i0);
        float4 A = p4[0], B = p4[1], C = p4[2];
        px[0]=A.x; py[0]=A.y; pz[0]=A.z;
        px[1]=A.w; py[1]=B.x; pz[1]=B.y;
        px[2]=B.z; py[2]=B.w; pz[2]=C.x;
        px[3]=C.y; py[3]=C.z; pz[3]=C.w;
    } else {
#pragma unroll
        for (int p = 0; p < NPT; ++p) {
            int ip = min(i0 + p, n - 1);
            px[p] = positions[3 * ip + 0];
            py[p] = positions[3 * ip + 1];
            pz[p] = positions[3 * ip + 2];
        }
    }

    float wA[NPT][3], wB[NPT][3];
    int bidx[NPT][8];
    int li[NPT][8];
#pragma unroll
    for (int p = 0; p < NPT; ++p) {
        float xc[3];
        xc[0] = (px[p] + 1.0f) * 0.5f * 255.0f;
        xc[1] = (py[p] + 1.0f) * 0.5f * 255.0f;
        xc[2] = (pz[p] + 1.0f) * 0.5f * 255.0f;
        int base[3];
#pragma unroll
        for (int a = 0; a < 3; ++a) {
            float bf = fminf(fmaxf(floorf(xc[a]), 0.0f), 254.0f);
            float fr = xc[a] - bf;
            wA[p][a] = 1.0f - fr;
            wB[p][a] = fr;
            base[a] = (int)bf;
        }
#pragma unroll
        for (int c = 0; c < 8; ++c) {
            int dx = (c >> 2) & 1, dy = (c >> 1) & 1, dz = c & 1;
            int cx = base[0] + dx, cy = base[1] + dy, cz = base[2] + dz;
            bidx[p][c] = stab[((cx >> 3) * GRID_RES + (cy >> 3)) * GRID_RES + (cz >> 3)];
            li[p][c] = ((cx & 7) * GRID_DIM + (cy & 7)) * GRID_DIM + (cz & 7);
        }
    }
    float e[NPT][8];
#pragma unroll
    for (int p = 0; p < NPT; ++p)
#pragma unroll
        for (int c = 0; c < 8; ++c) {
            int b = bidx[p][c] > 0 ? bidx[p][c] : 0;
            e[p][c] = embeddings[b * EMB_VOL + li[p][c]];
        }
    const float scale = 127.5f;
    float acc[NPT], gxv[NPT], gyv[NPT], gzv[NPT], mk[NPT];
#pragma unroll
    for (int p = 0; p < NPT; ++p) {
        float a = 0.0f, gx = 0.0f, gy = 0.0f, gz = 0.0f;
        bool vall = true;
#pragma unroll
        for (int c = 0; c < 8; ++c) {
            int dx = (c >> 2) & 1, dy = (c >> 1) & 1, dz = c & 1;
            bool valid = bidx[p][c] >= 0;
            vall = vall && valid;
            float ev = valid ? e[p][c] : 0.0f;
            float wx = dx ? wB[p][0] : wA[p][0];
            float wy = dy ? wB[p][1] : wA[p][1];
            float wz = dz ? wB[p][2] : wA[p][2];
            a += wx * wy * wz * ev;
            float tgx = wy * wz * ev;
            float tgy = wx * wz * ev;
            float tgz = wx * wy * ev;
            gx += dx ? tgx : -tgx;
            gy += dy ? tgy : -tgy;
            gz += dz ? tgz : -tgz;
        }
        acc[p] = a; gxv[p] = scale * gx; gyv[p] = scale * gy; gzv[p] = scale * gz;
        mk[p] = vall ? 1.0f : 0.0f;
    }
    float* out_emb  = out;
    float* out_grad = out + (size_t)n;
    float* out_mask = out + 4 * (size_t)n;
    if (full) {
        *reinterpret_cast<float4*>(out_emb + i0) =
            make_float4(acc[0], acc[1], acc[2], acc[3]);
        float4* g4 = reinterpret_cast<float4*>(out_grad + 3 * (size_t)i0);
        g4[0] = make_float4(gxv[0], gyv[0], gzv[0], gxv[1]);
        g4[1] = make_float4(gyv[1], gzv[1], gxv[2], gyv[2]);
        g4[2] = make_float4(gzv[2], gxv[3], gyv[3], gzv[3]);
        *reinterpret_cast<float4*>(out_mask + i0) =
            make_float4(mk[0], mk[1], mk[2], mk[3]);
    } else {
#pragma unroll
        for (int p = 0; p < NPT; ++p) {
            int ip = i0 + p;
            if (ip < n) {
                out_emb[ip] = acc[p];
                out_grad[3 * ip + 0] = gxv[p];
                out_grad[3 * ip + 1] = gyv[p];
                out_grad[3 * ip + 2] = gzv[p];
                out_mask[ip] = mk[p];
            }
        }
    }
}

extern "C" void kernel_launch(void* const* d_in, const int* in_sizes, int n_in,
                              void* d_out, int out_size, void* d_ws, size_t ws_size,
                              hipStream_t stream) {
    const float* positions   = (const float*)d_in[0];
    const float* embeddings  = (const float*)d_in[1];
    const int*   block_table = (const int*)d_in[2];

    int n = in_sizes[0] / 3;
    int nblocks = in_sizes[1] / EMB_VOL;     // EMB_DIM == 1
    size_t cube_bytes = (size_t)nblocks * EMB_VOL * sizeof(uint4);   // ~98 MB
    float* out = (float*)d_out;

    if (ws_size >= cube_bytes) {
        uint4* cube = (uint4*)d_ws;
        build_cubes<<<(TAB_N * 64 + 255) / 256, 256, 0, stream>>>(
            embeddings, block_table, cube);
        int nq = (n + NPT - 1) / NPT;
        int grid = 512;                       // persistent, 2 WGs/CU
        int maxg = (nq + BLOCK - 1) / BLOCK;
        if (grid > maxg) grid = maxg;
        interp_cubes<<<grid, BLOCK, 0, stream>>>(
            positions, embeddings, block_table, cube, out, n);
    } else {
        int nthreads = (n + NPT - 1) / NPT;
        int grid = (nthreads + BLOCK - 1) / BLOCK;
        neural_poisson_interp<<<grid, BLOCK, 0, stream>>>(
            positions, embeddings, block_table, out, n);
    }
}